// Round 1
// baseline (123.680 us; speedup 1.0000x reference)
//
#include <hip/hip_runtime.h>

// ---------------------------------------------------------------------------
// NeuralTheoremProver depth-1 score, MI355X.
//
//   score[b] = (1/E) * sum_z S1[b,z] * s2[b,z]
//   S1[b,z]  = sum_r sqrt(max(C1[b,r] + G[z,r] - 2*hz[b,z], 0))   (sign folded)
//   s2[b,z]  = sqrt(max(G2[z] + C2[b] - 2*zt[b,z], 0))
//   hz = H @ E^T, zt = T @ E^T  -> bf16 MFMA 16x16x32 (gemm_bt pattern)
//
// ws layout: Ebf[E][128] bf16 | Hbf[B][128] | Tbf[B][128] | Gz[E][16] f32 |
//            G2[E] | C1[B][16] | C2[B]
// ---------------------------------------------------------------------------

typedef __attribute__((ext_vector_type(8))) short short8;   // 8 x bf16 (4 VGPR)
typedef __attribute__((ext_vector_type(4))) float f32x4;

__device__ inline unsigned short f2bf(float f) {            // RNE fp32->bf16
  unsigned int u = __float_as_uint(f);
  u += 0x7fffu + ((u >> 16) & 1u);
  return (unsigned short)(u >> 16);
}

__device__ inline float wred64(float v) {                   // full-wave sum
#pragma unroll
  for (int o = 32; o > 0; o >>= 1) v += __shfl_xor(v, o, 64);
  return v;
}

__global__ void ntp_zero(float* out, int n) {
  int i = blockIdx.x * blockDim.x + threadIdx.x;
  if (i < n) out[i] = 0.f;
}

// One wave per entity z: bf16 cast + zz/zq/rz reductions -> G2, Gz.
__global__ __launch_bounds__(64) void ntp_pre_entity(
    const float* __restrict__ Etab, const float* __restrict__ rules,
    const int* __restrict__ qrelp, unsigned short* __restrict__ Ebf,
    float* __restrict__ Gz, float* __restrict__ G2) {
  const int z = blockIdx.x, tid = threadIdx.x;
  const float* e = Etab + (size_t)z * 128;
  float e0 = e[tid], e1 = e[tid + 64];
  Ebf[(size_t)z * 128 + tid]      = f2bf(e0);
  Ebf[(size_t)z * 128 + tid + 64] = f2bf(e1);
  float zz = wred64(e0 * e0 + e1 * e1);
  const int qrel = qrelp[0];
  const float* q = rules + (size_t)qrel * 128;
  float q0 = q[tid], q1 = q[tid + 64];
  float qq = wred64(q0 * q0 + q1 * q1);
  float zq = wred64(e0 * q0 + e1 * q1);
  if (tid == 0) G2[z] = zz + 2.f * zq + qq;
  for (int r = 0; r < 16; ++r) {
    const float* rp = rules + (size_t)r * 128;
    float r0 = rp[tid], r1 = rp[tid + 64];
    float rz = wred64(e0 * r0 + e1 * r1);
    if (tid == 0) Gz[(size_t)z * 16 + r] = zz - 2.f * rz;
  }
}

// One wave per batch row b: gather h/t, bf16 cast, C1/C2.
__global__ __launch_bounds__(64) void ntp_pre_b(
    const float* __restrict__ Etab, const float* __restrict__ rules,
    const int* __restrict__ head, const int* __restrict__ tail,
    const int* __restrict__ qrelp, unsigned short* __restrict__ Hbf,
    unsigned short* __restrict__ Tbf, float* __restrict__ C1,
    float* __restrict__ C2) {
  const int b = blockIdx.x, tid = threadIdx.x;
  const int hi = head[b], ti = tail[b];
  const float* h = Etab + (size_t)hi * 128;
  const float* t = Etab + (size_t)ti * 128;
  float h0 = h[tid], h1 = h[tid + 64];
  float t0 = t[tid], t1 = t[tid + 64];
  Hbf[(size_t)b * 128 + tid]      = f2bf(h0);
  Hbf[(size_t)b * 128 + tid + 64] = f2bf(h1);
  Tbf[(size_t)b * 128 + tid]      = f2bf(t0);
  Tbf[(size_t)b * 128 + tid + 64] = f2bf(t1);
  float hh = wred64(h0 * h0 + h1 * h1);
  float tt = wred64(t0 * t0 + t1 * t1);
  const int qrel = qrelp[0];
  const float* q = rules + (size_t)qrel * 128;
  float q0 = q[tid], q1 = q[tid + 64];
  float qt = wred64(t0 * q0 + t1 * q1);
  if (tid == 0) C2[b] = tt - 2.f * qt;
  for (int r = 0; r < 16; ++r) {
    const float* rp = rules + (size_t)r * 128;
    float r0 = rp[tid], r1 = rp[tid + 64];
    float rr = wred64(r0 * r0 + r1 * r1);
    float hr = wred64(h0 * r0 + h1 * r1);
    if (tid == 0) C1[(size_t)b * 16 + r] = hh + rr + 2.f * hr;
  }
}

// Main fused kernel. Block = 32 b x 256 z (8 chunks of 32 z).
// 4 waves: wave w -> b-half (w>>1), z-half (w&1); each owns a 16x16 MFMA tile.
// MFMA layouts (guide, m89/m92-verified):
//   A[m=lane&15][k=quad*8+j], B[k=quad*8+j][n=lane&15], D[m=quad*4+reg][n=lane&15]
__global__ __launch_bounds__(256, 4) void ntp_main(
    const unsigned short* __restrict__ Ebf, const unsigned short* __restrict__ Hbf,
    const unsigned short* __restrict__ Tbf, const float* __restrict__ Gz,
    const float* __restrict__ G2, const float* __restrict__ C1,
    const float* __restrict__ C2, float* __restrict__ out, int Ecount) {
  // Row pads: sEz 128+8 bf16 (272 B stride -> 2-way bank alias = free),
  // sGz stride 36 f32 (144 B, 16B-aligned, 2-way alias).
  __shared__ __align__(16) unsigned short sEz[32][136];
  __shared__ __align__(16) float sGz[32][36];
  __shared__ __align__(16) float sG2[32];
  __shared__ __align__(16) float sC1[32][16];
  __shared__ __align__(16) float sC2[32];

  const int tid   = threadIdx.x;
  const int lane  = tid & 63, wave = tid >> 6;
  const int bhalf = wave >> 1, zhalf = wave & 1;
  const int quad  = lane >> 4, lm = lane & 15;
  const int b_base = blockIdx.x * 32;
  const int z_base = blockIdx.y * 256;

  // Stage C1/C2 for this b-tile once.
  if (tid < 128) {
    *reinterpret_cast<f32x4*>(&sC1[tid >> 2][(tid & 3) * 4]) =
        *reinterpret_cast<const f32x4*>(&C1[(size_t)(b_base + (tid >> 2)) * 16 + (tid & 3) * 4]);
  }
  if (tid < 32) sC2[tid] = C2[b_base + tid];

  // A-fragments (H and T rows for this wave's 16 b's) live in registers all kernel.
  short8 hfrag[4], tfrag[4];
  {
    const size_t brow = (size_t)(b_base + bhalf * 16 + lm) * 128 + quad * 8;
    const unsigned short* hp = Hbf + brow;
    const unsigned short* tp = Tbf + brow;
#pragma unroll
    for (int k4 = 0; k4 < 4; ++k4) {
      hfrag[k4] = *reinterpret_cast<const short8*>(hp + k4 * 32);
      tfrag[k4] = *reinterpret_cast<const short8*>(tp + k4 * 32);
    }
  }

  const int z_loc = zhalf * 16 + lm;
  const float scale = 1.0f / (float)Ecount;
  f32x4 acc_out = {0.f, 0.f, 0.f, 0.f};

  for (int c = 0; c < 8; ++c) {
    const int z0 = z_base + c * 32;
    __syncthreads();  // protects prior-iter reads (and initial C1/C2 staging)
    {               // stage Ez chunk: 32 rows x 256 B, coalesced 16 B/thread x2
      int u = tid;
#pragma unroll
      for (int rep = 0; rep < 2; ++rep, u += 256) {
        int row = u >> 4, col = u & 15;
        *reinterpret_cast<short8*>(&sEz[row][col * 8]) =
            *reinterpret_cast<const short8*>(Ebf + (size_t)(z0 + row) * 128 + col * 8);
      }
    }
    if (tid < 128) {
      int row = tid >> 2, col = tid & 3;
      *reinterpret_cast<f32x4*>(&sGz[row][col * 4]) =
          *reinterpret_cast<const f32x4*>(&Gz[(size_t)(z0 + row) * 16 + col * 4]);
    }
    if (tid < 32) sG2[tid] = G2[z0 + tid];
    __syncthreads();

    // hz/zt 16x16 tiles: 4 K-steps x 2 MFMAs, B-frag shared between them.
    f32x4 acc_hz = {0.f, 0.f, 0.f, 0.f};
    f32x4 acc_zt = {0.f, 0.f, 0.f, 0.f};
#pragma unroll
    for (int k4 = 0; k4 < 4; ++k4) {
      short8 ef = *reinterpret_cast<const short8*>(&sEz[z_loc][k4 * 32 + quad * 8]);
      acc_hz = __builtin_amdgcn_mfma_f32_16x16x32_bf16(hfrag[k4], ef, acc_hz, 0, 0, 0);
      acc_zt = __builtin_amdgcn_mfma_f32_16x16x32_bf16(tfrag[k4], ef, acc_zt, 0, 0, 0);
    }

    // Epilogue: lane owns z = z_loc (fixed) and 4 b's (quad*4+reg).
    f32x4 gr[4];
#pragma unroll
    for (int i = 0; i < 4; ++i)
      gr[i] = *reinterpret_cast<const f32x4*>(&sGz[z_loc][i * 4]);
    const float g2v = sG2[z_loc];
#pragma unroll
    for (int reg = 0; reg < 4; ++reg) {
      const int b_loc = bhalf * 16 + quad * 4 + reg;
      const float hz = acc_hz[reg], zt = acc_zt[reg];
      const float sq2 = g2v + sC2[b_loc] - 2.f * zt;
      const float s2 = __builtin_amdgcn_sqrtf(fmaxf(sq2, 0.f));
      f32x4 c1q[4];
#pragma unroll
      for (int i = 0; i < 4; ++i)
        c1q[i] = *reinterpret_cast<const f32x4*>(&sC1[b_loc][i * 4]);  // broadcast
      const float m2hz = -2.f * hz;
      float S1 = 0.f;
#pragma unroll
      for (int r = 0; r < 16; ++r) {
        const float sq1 = (c1q[r >> 2][r & 3] + gr[r >> 2][r & 3]) + m2hz;
        S1 += __builtin_amdgcn_sqrtf(fmaxf(sq1, 0.f));
      }
      acc_out[reg] += S1 * s2;  // (-S1)*(-s2) = S1*s2
    }
  }

  // Reduce over the 16 n-lanes, then one atomic per (b, z-split).
#pragma unroll
  for (int reg = 0; reg < 4; ++reg) {
    float v = acc_out[reg];
    v += __shfl_xor(v, 1, 16);
    v += __shfl_xor(v, 2, 16);
    v += __shfl_xor(v, 4, 16);
    v += __shfl_xor(v, 8, 16);
    if (lm == 0)
      atomicAdd(&out[b_base + bhalf * 16 + quad * 4 + reg], v * scale);
  }
}

extern "C" void kernel_launch(void* const* d_in, const int* in_sizes, int n_in,
                              void* d_out, int out_size, void* d_ws, size_t ws_size,
                              hipStream_t stream) {
  const int* head  = (const int*)d_in[0];
  const int* tail  = (const int*)d_in[1];
  const int* qrel  = (const int*)d_in[2];
  // d_in[3] = depth (unused at depth==1 closed form)
  const float* Etab  = (const float*)d_in[4];
  const float* rules = (const float*)d_in[5];
  const int B = in_sizes[0];
  const int E = in_sizes[4] / 128;
  float* out = (float*)d_out;

  char* ws = (char*)d_ws;
  unsigned short* Ebf = (unsigned short*)ws;                       // E*128*2 B
  unsigned short* Hbf = (unsigned short*)(ws + (size_t)E * 256);   // B*128*2 B
  unsigned short* Tbf = Hbf + (size_t)B * 128;                     // B*128*2 B
  float* Gz = (float*)(ws + (size_t)E * 256 + (size_t)B * 512);    // E*16*4 B
  float* G2 = Gz + (size_t)E * 16;                                 // E*4 B
  float* C1 = G2 + E;                                              // B*16*4 B
  float* C2 = C1 + (size_t)B * 16;                                 // B*4 B

  ntp_zero<<<(B + 255) / 256, 256, 0, stream>>>(out, B);
  ntp_pre_entity<<<E, 64, 0, stream>>>(Etab, rules, qrel, Ebf, Gz, G2);
  ntp_pre_b<<<B, 64, 0, stream>>>(Etab, rules, head, tail, qrel, Hbf, Tbf, C1, C2);
  ntp_main<<<dim3(B / 32, E / 256), 256, 0, stream>>>(Ebf, Hbf, Tbf, Gz, G2, C1,
                                                      C2, out, E);
}

// Round 2
// 120.447 us; speedup vs baseline: 1.0268x; 1.0268x over previous
//
#include <hip/hip_runtime.h>

// ---------------------------------------------------------------------------
// NeuralTheoremProver depth-1 score, MI355X.  Round 2.
//
//   score[b] = (1/E) * sum_z S1[b,z] * s2[b,z]
//   S1[b,z]  = sum_r sqrt(max(C1[b,r] + Gz[z,r] - 2*hz[b,z], 0))
//   s2[b,z]  = sqrt(max(G2[z] + C2[b] - 2*zt[b,z], 0))
//   hz = H @ E^T, zt = T @ E^T  -> bf16 MFMA 16x16x32 (gemm_bt pattern)
//
// R2 changes vs R1:
//  * precompute rewritten: per-thread fp32x4 dots, NO wave reductions
//    (R1 was ds_swizzle-latency-bound: 19 serial wred64/wave x 8192 waves).
//    qrel trick: lane r==qrel has rv==q, so its rz==z.q and rr==q.q — G2/C2
//    come free with zero divergence.
//  * all precompute + out-zeroing fused into ONE kernel (2 dispatches total).
//  * main: launch_bounds (256,4)->(256,2) (R1 capped VGPR at 128 -> likely
//    spills); C1/C2 explicitly hoisted to registers (chunk-invariant),
//    removing 16 ds_read_b128 per chunk.
// ---------------------------------------------------------------------------

typedef __attribute__((ext_vector_type(8))) short short8;   // 8 x bf16 (4 VGPR)
typedef __attribute__((ext_vector_type(4))) float f32x4;

__device__ inline unsigned short f2bf(float f) {            // RNE fp32->bf16
  unsigned int u = __float_as_uint(f);
  u += 0x7fffu + ((u >> 16) & 1u);
  return (unsigned short)(u >> 16);
}

// One fused precompute kernel. Block = 256 threads = 16 rows x 16 r-lanes.
// Blocks [0, nEB)   : entity rows  -> Ebf, Gz, G2
// Blocks [nEB, end) : batch rows   -> Hbf, Tbf, C1, C2, out=0
__global__ __launch_bounds__(256) void ntp_pre(
    const float* __restrict__ Etab, const float* __restrict__ rules,
    const int* __restrict__ head, const int* __restrict__ tail,
    const int* __restrict__ qrelp, unsigned short* __restrict__ Ebf,
    unsigned short* __restrict__ Hbf, unsigned short* __restrict__ Tbf,
    float* __restrict__ Gz, float* __restrict__ G2, float* __restrict__ C1,
    float* __restrict__ C2, float* __restrict__ out, int nEB) {
  const int tid = threadIdx.x;
  const int gl = tid >> 4;          // row within this block's 16-row tile
  const int r  = tid & 15;          // rule index
  const int qrel = qrelp[0];
  const float* rp = rules + (size_t)r * 128;

  if ((int)blockIdx.x < nEB) {
    const int z = blockIdx.x * 16 + gl;
    const float* ez = Etab + (size_t)z * 128;
    float rz = 0.f, zz = 0.f, rr = 0.f;
#pragma unroll
    for (int k = 0; k < 128; k += 4) {
      f32x4 ev = *reinterpret_cast<const f32x4*>(ez + k);
      f32x4 rv = *reinterpret_cast<const f32x4*>(rp + k);
#pragma unroll
      for (int j = 0; j < 4; ++j) {
        rz += ev[j] * rv[j];
        zz += ev[j] * ev[j];
        rr += rv[j] * rv[j];
      }
    }
    Gz[(size_t)z * 16 + r] = zz - 2.f * rz;                 // zz - 2 z.r
    if (r == qrel) G2[z] = zz + 2.f * rz + rr;              // zz + 2 z.q + qq
    // bf16 cast: thread handles row gl, cols r*8 .. r*8+7 (vector store)
    const float* src = ez + r * 8;
    short8 o;
#pragma unroll
    for (int j = 0; j < 8; ++j) o[j] = (short)f2bf(src[j]);
    *reinterpret_cast<short8*>(Ebf + (size_t)z * 128 + r * 8) = o;
  } else {
    const int b = (blockIdx.x - nEB) * 16 + gl;
    const int hi = head[b], ti = tail[b];
    const float* hp = Etab + (size_t)hi * 128;
    const float* tp = Etab + (size_t)ti * 128;
    float hr = 0.f, tq = 0.f, hh = 0.f, tt = 0.f, rr = 0.f;
#pragma unroll
    for (int k = 0; k < 128; k += 4) {
      f32x4 hv = *reinterpret_cast<const f32x4*>(hp + k);
      f32x4 tv = *reinterpret_cast<const f32x4*>(tp + k);
      f32x4 rv = *reinterpret_cast<const f32x4*>(rp + k);
#pragma unroll
      for (int j = 0; j < 4; ++j) {
        hr += hv[j] * rv[j];
        tq += tv[j] * rv[j];
        hh += hv[j] * hv[j];
        tt += tv[j] * tv[j];
        rr += rv[j] * rv[j];
      }
    }
    C1[(size_t)b * 16 + r] = hh + rr + 2.f * hr;            // hh + rr + 2 h.r
    if (r == qrel) C2[b] = tt - 2.f * tq;                   // tt - 2 q.t
    if (r == 0) out[b] = 0.f;
    short8 oh, ot;
    const float* hsrc = hp + r * 8;
    const float* tsrc = tp + r * 8;
#pragma unroll
    for (int j = 0; j < 8; ++j) {
      oh[j] = (short)f2bf(hsrc[j]);
      ot[j] = (short)f2bf(tsrc[j]);
    }
    *reinterpret_cast<short8*>(Hbf + (size_t)b * 128 + r * 8) = oh;
    *reinterpret_cast<short8*>(Tbf + (size_t)b * 128 + r * 8) = ot;
  }
}

// Main fused kernel. Block = 32 b x 256 z (8 chunks of 32 z).
// 4 waves: wave w -> b-half (w>>1), z-half (w&1); each owns a 16x16 MFMA tile.
// MFMA layouts (m89/m92-verified):
//   A[m=lane&15][k=quad*8+j], B[k=quad*8+j][n=lane&15], D[m=quad*4+reg][n=lane&15]
__global__ __launch_bounds__(256, 2) void ntp_main(
    const unsigned short* __restrict__ Ebf, const unsigned short* __restrict__ Hbf,
    const unsigned short* __restrict__ Tbf, const float* __restrict__ Gz,
    const float* __restrict__ G2, const float* __restrict__ C1,
    const float* __restrict__ C2, float* __restrict__ out, int Ecount) {
  // Row pads: sEz 128+8 bf16 (272 B stride -> 2-way bank alias = free),
  // sGz stride 36 f32 (144 B, 16B-aligned, 2-way alias).
  __shared__ __align__(16) unsigned short sEz[32][136];
  __shared__ __align__(16) float sGz[32][36];
  __shared__ __align__(16) float sG2[32];
  __shared__ __align__(16) float sC1[32][16];
  __shared__ __align__(16) float sC2[32];

  const int tid   = threadIdx.x;
  const int lane  = tid & 63, wave = tid >> 6;
  const int bhalf = wave >> 1, zhalf = wave & 1;
  const int quad  = lane >> 4, lm = lane & 15;
  const int b_base = blockIdx.x * 32;
  const int z_base = blockIdx.y * 256;

  // Stage C1/C2 for this b-tile once, then hoist into registers.
  if (tid < 128) {
    *reinterpret_cast<f32x4*>(&sC1[tid >> 2][(tid & 3) * 4]) =
        *reinterpret_cast<const f32x4*>(&C1[(size_t)(b_base + (tid >> 2)) * 16 + (tid & 3) * 4]);
  }
  if (tid < 32) sC2[tid] = C2[b_base + tid];

  // A-fragments (H and T rows for this wave's 16 b's) register-resident.
  short8 hfrag[4], tfrag[4];
  {
    const size_t brow = (size_t)(b_base + bhalf * 16 + lm) * 128 + quad * 8;
    const unsigned short* hp = Hbf + brow;
    const unsigned short* tp = Tbf + brow;
#pragma unroll
    for (int k4 = 0; k4 < 4; ++k4) {
      hfrag[k4] = *reinterpret_cast<const short8*>(hp + k4 * 32);
      tfrag[k4] = *reinterpret_cast<const short8*>(tp + k4 * 32);
    }
  }

  __syncthreads();
  // Chunk-invariant per-lane constants: C1 row quad (64 regs) + C2 (4 regs).
  f32x4 c1q[4][4];
  float c2v[4];
#pragma unroll
  for (int reg = 0; reg < 4; ++reg) {
    const int b_loc = bhalf * 16 + quad * 4 + reg;
#pragma unroll
    for (int i = 0; i < 4; ++i)
      c1q[reg][i] = *reinterpret_cast<const f32x4*>(&sC1[b_loc][i * 4]);
    c2v[reg] = sC2[b_loc];
  }

  const int z_loc = zhalf * 16 + lm;
  const float scale = 1.0f / (float)Ecount;
  f32x4 acc_out = {0.f, 0.f, 0.f, 0.f};

  for (int c = 0; c < 8; ++c) {
    const int z0 = z_base + c * 32;
    __syncthreads();  // protect prior-iter sEz/sGz reads before re-staging
    {                 // stage Ez chunk: 32 rows x 256 B, 16 B/thread x2
      int u = tid;
#pragma unroll
      for (int rep = 0; rep < 2; ++rep, u += 256) {
        int row = u >> 4, col = u & 15;
        *reinterpret_cast<short8*>(&sEz[row][col * 8]) =
            *reinterpret_cast<const short8*>(Ebf + (size_t)(z0 + row) * 128 + col * 8);
      }
    }
    if (tid < 128) {
      int row = tid >> 2, col = tid & 3;
      *reinterpret_cast<f32x4*>(&sGz[row][col * 4]) =
          *reinterpret_cast<const f32x4*>(&Gz[(size_t)(z0 + row) * 16 + col * 4]);
    }
    if (tid < 32) sG2[tid] = G2[z0 + tid];
    __syncthreads();

    // hz/zt 16x16 tiles: 4 K-steps x 2 MFMAs, B-frag shared between them.
    f32x4 acc_hz = {0.f, 0.f, 0.f, 0.f};
    f32x4 acc_zt = {0.f, 0.f, 0.f, 0.f};
#pragma unroll
    for (int k4 = 0; k4 < 4; ++k4) {
      short8 ef = *reinterpret_cast<const short8*>(&sEz[z_loc][k4 * 32 + quad * 8]);
      acc_hz = __builtin_amdgcn_mfma_f32_16x16x32_bf16(hfrag[k4], ef, acc_hz, 0, 0, 0);
      acc_zt = __builtin_amdgcn_mfma_f32_16x16x32_bf16(tfrag[k4], ef, acc_zt, 0, 0, 0);
    }

    // Epilogue: lane owns z = z_loc (fixed) and 4 b's (quad*4+reg).
    f32x4 gr[4];
#pragma unroll
    for (int i = 0; i < 4; ++i)
      gr[i] = *reinterpret_cast<const f32x4*>(&sGz[z_loc][i * 4]);
    const float g2v = sG2[z_loc];
#pragma unroll
    for (int reg = 0; reg < 4; ++reg) {
      const float hz = acc_hz[reg], zt = acc_zt[reg];
      const float sq2 = g2v + c2v[reg] - 2.f * zt;
      const float s2 = __builtin_amdgcn_sqrtf(fmaxf(sq2, 0.f));
      const float m2hz = -2.f * hz;
      float S1 = 0.f;
#pragma unroll
      for (int i = 0; i < 4; ++i)
#pragma unroll
        for (int j = 0; j < 4; ++j) {
          const float sq1 = (c1q[reg][i][j] + gr[i][j]) + m2hz;
          S1 += __builtin_amdgcn_sqrtf(fmaxf(sq1, 0.f));
        }
      acc_out[reg] += S1 * s2;  // (-S1)*(-s2) = S1*s2
    }
  }

  // Reduce over the 16 n-lanes, then one atomic per (b, z-split).
#pragma unroll
  for (int reg = 0; reg < 4; ++reg) {
    float v = acc_out[reg];
    v += __shfl_xor(v, 1, 16);
    v += __shfl_xor(v, 2, 16);
    v += __shfl_xor(v, 4, 16);
    v += __shfl_xor(v, 8, 16);
    if (lm == 0)
      atomicAdd(&out[b_base + bhalf * 16 + quad * 4 + reg], v * scale);
  }
}

extern "C" void kernel_launch(void* const* d_in, const int* in_sizes, int n_in,
                              void* d_out, int out_size, void* d_ws, size_t ws_size,
                              hipStream_t stream) {
  const int* head  = (const int*)d_in[0];
  const int* tail  = (const int*)d_in[1];
  const int* qrel  = (const int*)d_in[2];
  // d_in[3] = depth (unused at depth==1 closed form)
  const float* Etab  = (const float*)d_in[4];
  const float* rules = (const float*)d_in[5];
  const int B = in_sizes[0];
  const int E = in_sizes[4] / 128;
  float* out = (float*)d_out;

  char* ws = (char*)d_ws;
  unsigned short* Ebf = (unsigned short*)ws;                       // E*128*2 B
  unsigned short* Hbf = (unsigned short*)(ws + (size_t)E * 256);   // B*128*2 B
  unsigned short* Tbf = Hbf + (size_t)B * 128;                     // B*128*2 B
  float* Gz = (float*)(ws + (size_t)E * 256 + (size_t)B * 512);    // E*16*4 B
  float* G2 = Gz + (size_t)E * 16;                                 // E*4 B
  float* C1 = G2 + E;                                              // B*16*4 B
  float* C2 = C1 + (size_t)B * 16;                                 // B*4 B

  const int nEB = E / 16;                                          // 512
  const int nBB = B / 16;                                          // 64
  ntp_pre<<<nEB + nBB, 256, 0, stream>>>(Etab, rules, head, tail, qrel, Ebf,
                                         Hbf, Tbf, Gz, G2, C1, C2, out, nEB);
  ntp_main<<<dim3(B / 32, E / 256), 256, 0, stream>>>(Ebf, Hbf, Tbf, Gz, G2, C1,
                                                      C2, out, E);
}

// Round 3
// 113.665 us; speedup vs baseline: 1.0881x; 1.0597x over previous
//
#include <hip/hip_runtime.h>

// ---------------------------------------------------------------------------
// NeuralTheoremProver depth-1 score, MI355X.  Round 3.
//
//   score[b] = (1/E) * sum_z S1[b,z] * s2[b,z]
//   S1[b,z]  = sum_r sqrt(max(C1[b,r] + Gz[z,r] - 2*hz[b,z], 0))
//   s2[b,z]  = sqrt(max(G2[z] + C2[b] - 2*zt[b,z], 0))
//   hz = H @ E^T, zt = T @ E^T  -> bf16 MFMA 16x16x32
//
// R3 changes vs R2:
//  * main: NO in-loop barriers, no Ez/Gz LDS staging. R2 was latency-bound
//    (VALUBusy 45%, Occ 22%): 16 barriers/block lockstepped all waves.
//    Ez fragments + Gz/G2 now loaded straight from global in MFMA layout
//    (Ebf=2MB, Gz=512KB -> L2-resident; ~134MB L2 reads << 34.5 TB/s).
//    Only sC1 (2.5KB, row pad 20 f32 -> 2-way alias, free) stays in LDS
//    behind ONE startup barrier; reads are quad-broadcast.
//  * grid 1024 -> 2048 blocks (128 z/block, 4 chunks) for balance.
//  * pre: rules staged in LDS (was 16-distinct-line scattered VMEM loads).
// ---------------------------------------------------------------------------

typedef __attribute__((ext_vector_type(8))) short short8;   // 8 x bf16 (4 VGPR)
typedef __attribute__((ext_vector_type(4))) float f32x4;

__device__ inline unsigned short f2bf(float f) {            // RNE fp32->bf16
  unsigned int u = __float_as_uint(f);
  u += 0x7fffu + ((u >> 16) & 1u);
  return (unsigned short)(u >> 16);
}

// Fused precompute. Block = 256 threads = 16 rows x 16 r-lanes.
// Blocks [0, nEB)   : entity rows  -> Ebf, Gz, G2
// Blocks [nEB, end) : batch rows   -> Hbf, Tbf, C1, C2, out=0
__global__ __launch_bounds__(256) void ntp_pre(
    const float* __restrict__ Etab, const float* __restrict__ rules,
    const int* __restrict__ head, const int* __restrict__ tail,
    const int* __restrict__ qrelp, unsigned short* __restrict__ Ebf,
    unsigned short* __restrict__ Hbf, unsigned short* __restrict__ Tbf,
    float* __restrict__ Gz, float* __restrict__ G2, float* __restrict__ C1,
    float* __restrict__ C2, float* __restrict__ out, int nEB) {
  __shared__ __align__(16) float sR[16][132];   // rules, +4 pad -> 2-way alias
  const int tid = threadIdx.x;
  const int gl = tid >> 4;          // row within this block's 16-row tile
  const int r  = tid & 15;          // rule index
  const int qrel = qrelp[0];

  // Stage all 16 rule rows: 512 f32x4, 2 per thread.
#pragma unroll
  for (int rep = 0; rep < 2; ++rep) {
    int idx = tid + rep * 256;                  // f32x4 index
    int row = idx >> 5, colv = idx & 31;
    *reinterpret_cast<f32x4*>(&sR[row][colv * 4]) =
        *reinterpret_cast<const f32x4*>(rules + (size_t)row * 128 + colv * 4);
  }
  __syncthreads();

  if ((int)blockIdx.x < nEB) {
    const int z = blockIdx.x * 16 + gl;
    const float* ez = Etab + (size_t)z * 128;
    float rz = 0.f, zz = 0.f, rr = 0.f;
#pragma unroll
    for (int k = 0; k < 128; k += 4) {
      f32x4 ev = *reinterpret_cast<const f32x4*>(ez + k);
      f32x4 rv = *reinterpret_cast<const f32x4*>(&sR[r][k]);
#pragma unroll
      for (int j = 0; j < 4; ++j) {
        rz += ev[j] * rv[j];
        zz += ev[j] * ev[j];
        rr += rv[j] * rv[j];
      }
    }
    Gz[(size_t)z * 16 + r] = zz - 2.f * rz;                 // zz - 2 z.r
    if (r == qrel) G2[z] = zz + 2.f * rz + rr;              // zz + 2 z.q + qq
    const float* src = ez + r * 8;
    short8 o;
#pragma unroll
    for (int j = 0; j < 8; ++j) o[j] = (short)f2bf(src[j]);
    *reinterpret_cast<short8*>(Ebf + (size_t)z * 128 + r * 8) = o;
  } else {
    const int b = (blockIdx.x - nEB) * 16 + gl;
    const int hi = head[b], ti = tail[b];
    const float* hp = Etab + (size_t)hi * 128;
    const float* tp = Etab + (size_t)ti * 128;
    float hr = 0.f, tq = 0.f, hh = 0.f, tt = 0.f, rr = 0.f;
#pragma unroll
    for (int k = 0; k < 128; k += 4) {
      f32x4 hv = *reinterpret_cast<const f32x4*>(hp + k);
      f32x4 tv = *reinterpret_cast<const f32x4*>(tp + k);
      f32x4 rv = *reinterpret_cast<const f32x4*>(&sR[r][k]);
#pragma unroll
      for (int j = 0; j < 4; ++j) {
        hr += hv[j] * rv[j];
        tq += tv[j] * rv[j];
        hh += hv[j] * hv[j];
        tt += tv[j] * tv[j];
        rr += rv[j] * rv[j];
      }
    }
    C1[(size_t)b * 16 + r] = hh + rr + 2.f * hr;            // hh + rr + 2 h.r
    if (r == qrel) C2[b] = tt - 2.f * tq;                   // tt - 2 q.t
    if (r == 0) out[b] = 0.f;
    short8 oh, ot;
    const float* hsrc = hp + r * 8;
    const float* tsrc = tp + r * 8;
#pragma unroll
    for (int j = 0; j < 8; ++j) {
      oh[j] = (short)f2bf(hsrc[j]);
      ot[j] = (short)f2bf(tsrc[j]);
    }
    *reinterpret_cast<short8*>(Hbf + (size_t)b * 128 + r * 8) = oh;
    *reinterpret_cast<short8*>(Tbf + (size_t)b * 128 + r * 8) = ot;
  }
}

// Main fused kernel. Block = 32 b x 128 z (4 chunks of 32 z), barrier-free loop.
// 4 waves: wave w -> b-half (w>>1), z-half (w&1); each owns a 16x16 MFMA tile.
// MFMA layouts (m89/m92-verified):
//   A[m=lane&15][k=quad*8+j], B[k=quad*8+j][n=lane&15], D[m=quad*4+reg][n=lane&15]
__global__ __launch_bounds__(256, 3) void ntp_main(
    const unsigned short* __restrict__ Ebf, const unsigned short* __restrict__ Hbf,
    const unsigned short* __restrict__ Tbf, const float* __restrict__ Gz,
    const float* __restrict__ G2, const float* __restrict__ C1,
    const float* __restrict__ C2, float* __restrict__ out, int Ecount) {
  __shared__ __align__(16) float sC1[32][20];   // pad 20 -> quad reads 2-way alias

  const int tid   = threadIdx.x;
  const int lane  = tid & 63, wave = tid >> 6;
  const int bhalf = wave >> 1, zhalf = wave & 1;
  const int quad  = lane >> 4, lm = lane & 15;
  const int b_base = blockIdx.x * 32;
  const int z_base = blockIdx.y * 128;

  // Stage C1 b-tile once (only LDS use; single startup barrier).
  if (tid < 128) {
    int row = tid >> 2, colv = tid & 3;
    *reinterpret_cast<f32x4*>(&sC1[row][colv * 4]) =
        *reinterpret_cast<const f32x4*>(&C1[(size_t)(b_base + row) * 16 + colv * 4]);
  }

  // A-fragments (H and T rows for this wave's 16 b's) register-resident.
  short8 hfrag[4], tfrag[4];
  {
    const size_t brow = (size_t)(b_base + bhalf * 16 + lm) * 128 + quad * 8;
    const unsigned short* hp = Hbf + brow;
    const unsigned short* tp = Tbf + brow;
#pragma unroll
    for (int k4 = 0; k4 < 4; ++k4) {
      hfrag[k4] = *reinterpret_cast<const short8*>(hp + k4 * 32);
      tfrag[k4] = *reinterpret_cast<const short8*>(tp + k4 * 32);
    }
  }

  // C2 for this lane's 4 b's -> 4 registers (b_loc independent of lm).
  float c2v[4];
#pragma unroll
  for (int reg = 0; reg < 4; ++reg)
    c2v[reg] = C2[b_base + bhalf * 16 + quad * 4 + reg];

  __syncthreads();   // sC1 ready; no further barriers.

  const int z_loc = zhalf * 16 + lm;
  const float scale = 1.0f / (float)Ecount;
  f32x4 acc_out = {0.f, 0.f, 0.f, 0.f};

  for (int c = 0; c < 4; ++c) {
    const int z = z_base + c * 32 + z_loc;     // this lane's entity column

    // B-fragments straight from global (L2-resident, MFMA layout native).
    const unsigned short* ep = Ebf + (size_t)z * 128 + quad * 8;
    f32x4 acc_hz = {0.f, 0.f, 0.f, 0.f};
    f32x4 acc_zt = {0.f, 0.f, 0.f, 0.f};
#pragma unroll
    for (int k4 = 0; k4 < 4; ++k4) {
      short8 ef = *reinterpret_cast<const short8*>(ep + k4 * 32);
      acc_hz = __builtin_amdgcn_mfma_f32_16x16x32_bf16(hfrag[k4], ef, acc_hz, 0, 0, 0);
      acc_zt = __builtin_amdgcn_mfma_f32_16x16x32_bf16(tfrag[k4], ef, acc_zt, 0, 0, 0);
    }

    // Per-z constants straight from global.
    f32x4 gr[4];
#pragma unroll
    for (int i = 0; i < 4; ++i)
      gr[i] = *reinterpret_cast<const f32x4*>(&Gz[(size_t)z * 16 + i * 4]);
    const float g2v = G2[z];

#pragma unroll
    for (int reg = 0; reg < 4; ++reg) {
      const int b_loc = bhalf * 16 + quad * 4 + reg;
      const float hz = acc_hz[reg], zt = acc_zt[reg];
      const float sq2 = g2v + c2v[reg] - 2.f * zt;
      const float s2 = __builtin_amdgcn_sqrtf(fmaxf(sq2, 0.f));
      const float m2hz = -2.f * hz;
      float S1 = 0.f;
#pragma unroll
      for (int i = 0; i < 4; ++i) {
        f32x4 c1v = *reinterpret_cast<const f32x4*>(&sC1[b_loc][i * 4]);  // bcast
#pragma unroll
        for (int j = 0; j < 4; ++j) {
          const float sq1 = (c1v[j] + gr[i][j]) + m2hz;
          S1 += __builtin_amdgcn_sqrtf(fmaxf(sq1, 0.f));
        }
      }
      acc_out[reg] += S1 * s2;  // (-S1)*(-s2) = S1*s2
    }
  }

  // Reduce over the 16 n-lanes, then one atomic per (b, z-block).
#pragma unroll
  for (int reg = 0; reg < 4; ++reg) {
    float v = acc_out[reg];
    v += __shfl_xor(v, 1, 16);
    v += __shfl_xor(v, 2, 16);
    v += __shfl_xor(v, 4, 16);
    v += __shfl_xor(v, 8, 16);
    if (lm == 0)
      atomicAdd(&out[b_base + bhalf * 16 + quad * 4 + reg], v * scale);
  }
}

extern "C" void kernel_launch(void* const* d_in, const int* in_sizes, int n_in,
                              void* d_out, int out_size, void* d_ws, size_t ws_size,
                              hipStream_t stream) {
  const int* head  = (const int*)d_in[0];
  const int* tail  = (const int*)d_in[1];
  const int* qrel  = (const int*)d_in[2];
  // d_in[3] = depth (unused at depth==1 closed form)
  const float* Etab  = (const float*)d_in[4];
  const float* rules = (const float*)d_in[5];
  const int B = in_sizes[0];
  const int E = in_sizes[4] / 128;
  float* out = (float*)d_out;

  char* ws = (char*)d_ws;
  unsigned short* Ebf = (unsigned short*)ws;                       // E*128*2 B
  unsigned short* Hbf = (unsigned short*)(ws + (size_t)E * 256);   // B*128*2 B
  unsigned short* Tbf = Hbf + (size_t)B * 128;                     // B*128*2 B
  float* Gz = (float*)(ws + (size_t)E * 256 + (size_t)B * 512);    // E*16*4 B
  float* G2 = Gz + (size_t)E * 16;                                 // E*4 B
  float* C1 = G2 + E;                                              // B*16*4 B
  float* C2 = C1 + (size_t)B * 16;                                 // B*4 B

  const int nEB = E / 16;                                          // 512
  const int nBB = B / 16;                                          // 64
  ntp_pre<<<nEB + nBB, 256, 0, stream>>>(Etab, rules, head, tail, qrel, Ebf,
                                         Hbf, Tbf, Gz, G2, C1, C2, out, nEB);
  ntp_main<<<dim3(B / 32, E / 128), 256, 0, stream>>>(Ebf, Hbf, Tbf, Gz, G2, C1,
                                                      C2, out, E);
}

// Round 4
// 106.760 us; speedup vs baseline: 1.1585x; 1.0647x over previous
//
#include <hip/hip_runtime.h>

// ---------------------------------------------------------------------------
// NeuralTheoremProver depth-1 score, MI355X.  Round 4.
//
//   score[b] = (1/E) * sum_z S1[b,z] * s2[b,z]
//   S1[b,z]  = sum_r sqrt(max(C1[b,r] + Gz[z,r] - 2*hz[b,z], 0))
//   s2[b,z]  = sqrt(max(G2[z] + C2[b] - 2*zt[b,z], 0))
//   hz = H @ E^T, zt = T @ E^T  -> bf16 MFMA 16x16x32
//
// R4 changes vs R3 (R3 post-mortem: VALUBusy 43% == 19us issue, rest is
// latency stall on scattered per-lane global gr/ef loads at only 8 waves/CU):
//  * ALL per-z data (Ez, Gz, G2) + C1 staged to LDS ONCE per block behind a
//    single startup barrier; compute loop reads only LDS (short latency,
//    <=2-way bank alias = free; c1/gr reads are same-address broadcasts).
//  * z-tile 128 -> 64 per block (2 chunks): LDS ~25 KB -> 4+ blocks/CU at
//    launch_bounds(256,4) -> 16 waves/CU (2x R3) for latency hiding.
//    Total staging traffic is tile-invariant (64 MB L2 reads grid-wide).
// ---------------------------------------------------------------------------

typedef __attribute__((ext_vector_type(8))) short short8;   // 8 x bf16 (4 VGPR)
typedef __attribute__((ext_vector_type(4))) float f32x4;

__device__ inline unsigned short f2bf(float f) {            // RNE fp32->bf16
  unsigned int u = __float_as_uint(f);
  u += 0x7fffu + ((u >> 16) & 1u);
  return (unsigned short)(u >> 16);
}

// Fused precompute. Block = 256 threads = 16 rows x 16 r-lanes.
// Blocks [0, nEB)   : entity rows  -> Ebf, Gz, G2
// Blocks [nEB, end) : batch rows   -> Hbf, Tbf, C1, C2, out=0
__global__ __launch_bounds__(256) void ntp_pre(
    const float* __restrict__ Etab, const float* __restrict__ rules,
    const int* __restrict__ head, const int* __restrict__ tail,
    const int* __restrict__ qrelp, unsigned short* __restrict__ Ebf,
    unsigned short* __restrict__ Hbf, unsigned short* __restrict__ Tbf,
    float* __restrict__ Gz, float* __restrict__ G2, float* __restrict__ C1,
    float* __restrict__ C2, float* __restrict__ out, int nEB) {
  __shared__ __align__(16) float sR[16][132];   // rules, +4 pad -> 2-way alias
  const int tid = threadIdx.x;
  const int gl = tid >> 4;          // row within this block's 16-row tile
  const int r  = tid & 15;          // rule index
  const int qrel = qrelp[0];

  // Stage all 16 rule rows: 512 f32x4, 2 per thread.
#pragma unroll
  for (int rep = 0; rep < 2; ++rep) {
    int idx = tid + rep * 256;                  // f32x4 index
    int row = idx >> 5, colv = idx & 31;
    *reinterpret_cast<f32x4*>(&sR[row][colv * 4]) =
        *reinterpret_cast<const f32x4*>(rules + (size_t)row * 128 + colv * 4);
  }
  __syncthreads();

  if ((int)blockIdx.x < nEB) {
    const int z = blockIdx.x * 16 + gl;
    const float* ez = Etab + (size_t)z * 128;
    float rz = 0.f, zz = 0.f, rr = 0.f;
#pragma unroll
    for (int k = 0; k < 128; k += 4) {
      f32x4 ev = *reinterpret_cast<const f32x4*>(ez + k);
      f32x4 rv = *reinterpret_cast<const f32x4*>(&sR[r][k]);
#pragma unroll
      for (int j = 0; j < 4; ++j) {
        rz += ev[j] * rv[j];
        zz += ev[j] * ev[j];
        rr += rv[j] * rv[j];
      }
    }
    Gz[(size_t)z * 16 + r] = zz - 2.f * rz;                 // zz - 2 z.r
    if (r == qrel) G2[z] = zz + 2.f * rz + rr;              // zz + 2 z.q + qq
    const float* src = ez + r * 8;
    short8 o;
#pragma unroll
    for (int j = 0; j < 8; ++j) o[j] = (short)f2bf(src[j]);
    *reinterpret_cast<short8*>(Ebf + (size_t)z * 128 + r * 8) = o;
  } else {
    const int b = (blockIdx.x - nEB) * 16 + gl;
    const int hi = head[b], ti = tail[b];
    const float* hp = Etab + (size_t)hi * 128;
    const float* tp = Etab + (size_t)ti * 128;
    float hr = 0.f, tq = 0.f, hh = 0.f, tt = 0.f, rr = 0.f;
#pragma unroll
    for (int k = 0; k < 128; k += 4) {
      f32x4 hv = *reinterpret_cast<const f32x4*>(hp + k);
      f32x4 tv = *reinterpret_cast<const f32x4*>(tp + k);
      f32x4 rv = *reinterpret_cast<const f32x4*>(&sR[r][k]);
#pragma unroll
      for (int j = 0; j < 4; ++j) {
        hr += hv[j] * rv[j];
        tq += tv[j] * rv[j];
        hh += hv[j] * hv[j];
        tt += tv[j] * tv[j];
        rr += rv[j] * rv[j];
      }
    }
    C1[(size_t)b * 16 + r] = hh + rr + 2.f * hr;            // hh + rr + 2 h.r
    if (r == qrel) C2[b] = tt - 2.f * tq;                   // tt - 2 q.t
    if (r == 0) out[b] = 0.f;
    short8 oh, ot;
    const float* hsrc = hp + r * 8;
    const float* tsrc = tp + r * 8;
#pragma unroll
    for (int j = 0; j < 8; ++j) {
      oh[j] = (short)f2bf(hsrc[j]);
      ot[j] = (short)f2bf(tsrc[j]);
    }
    *reinterpret_cast<short8*>(Hbf + (size_t)b * 128 + r * 8) = oh;
    *reinterpret_cast<short8*>(Tbf + (size_t)b * 128 + r * 8) = ot;
  }
}

// Main fused kernel. Block = 32 b x 64 z (2 chunks of 32 z).
// Stage-once to LDS, single barrier, barrier-free compute from LDS.
// 4 waves: wave w -> b-half (w>>1), z-half (w&1); each owns a 16x16 MFMA tile.
// MFMA layouts (m89/m92-verified):
//   A[m=lane&15][k=quad*8+j], B[k=quad*8+j][n=lane&15], D[m=quad*4+reg][n=lane&15]
__global__ __launch_bounds__(256, 4) void ntp_main(
    const unsigned short* __restrict__ Ebf, const unsigned short* __restrict__ Hbf,
    const unsigned short* __restrict__ Tbf, const float* __restrict__ Gz,
    const float* __restrict__ G2, const float* __restrict__ C1,
    const float* __restrict__ C2, float* __restrict__ out, int Ecount) {
  // Pads: sEz row 136 shorts (272B, bank shift 4/row -> 2-way alias = free),
  // sGz row 20 f32 (80B -> 2-way), sC1 row 20 f32 (reads are broadcasts).
  __shared__ __align__(16) unsigned short sEz[64][136];   // 17408 B
  __shared__ __align__(16) float sGz[64][20];             //  5120 B
  __shared__ __align__(16) float sG2[64];                 //   256 B
  __shared__ __align__(16) float sC1[32][20];             //  2560 B

  const int tid   = threadIdx.x;
  const int lane  = tid & 63, wave = tid >> 6;
  const int bhalf = wave >> 1, zhalf = wave & 1;
  const int quad  = lane >> 4, lm = lane & 15;
  const int b_base = blockIdx.x * 32;
  const int z_base = blockIdx.y * 64;

  // ---- one-shot staging (coalesced 16B/lane) ----
#pragma unroll
  for (int rep = 0; rep < 4; ++rep) {           // Ez: 64 rows x 256 B
    int c = tid + rep * 256;
    int row = c >> 4, col = c & 15;
    *reinterpret_cast<short8*>(&sEz[row][col * 8]) =
        *reinterpret_cast<const short8*>(Ebf + (size_t)(z_base + row) * 128 + col * 8);
  }
  {                                             // Gz: 64 rows x 64 B
    int row = tid >> 2, colv = tid & 3;
    *reinterpret_cast<f32x4*>(&sGz[row][colv * 4]) =
        *reinterpret_cast<const f32x4*>(Gz + (size_t)(z_base + row) * 16 + colv * 4);
  }
  if (tid < 64) sG2[tid] = G2[z_base + tid];
  if (tid < 128) {                              // C1: 32 rows x 64 B
    int row = tid >> 2, colv = tid & 3;
    *reinterpret_cast<f32x4*>(&sC1[row][colv * 4]) =
        *reinterpret_cast<const f32x4*>(&C1[(size_t)(b_base + row) * 16 + colv * 4]);
  }

  // A-fragments (H and T rows for this wave's 16 b's) register-resident.
  short8 hfrag[4], tfrag[4];
  {
    const size_t brow = (size_t)(b_base + bhalf * 16 + lm) * 128 + quad * 8;
    const unsigned short* hp = Hbf + brow;
    const unsigned short* tp = Tbf + brow;
#pragma unroll
    for (int k4 = 0; k4 < 4; ++k4) {
      hfrag[k4] = *reinterpret_cast<const short8*>(hp + k4 * 32);
      tfrag[k4] = *reinterpret_cast<const short8*>(tp + k4 * 32);
    }
  }

  // C2 for this lane's 4 b's -> registers (independent of lm).
  float c2v[4];
#pragma unroll
  for (int reg = 0; reg < 4; ++reg)
    c2v[reg] = C2[b_base + bhalf * 16 + quad * 4 + reg];

  __syncthreads();   // staging complete; no further barriers.

  const int z_loc = zhalf * 16 + lm;
  const float scale = 1.0f / (float)Ecount;
  f32x4 acc_out = {0.f, 0.f, 0.f, 0.f};

#pragma unroll
  for (int c = 0; c < 2; ++c) {
    const int zr = c * 32 + z_loc;              // LDS row for this lane's z

    f32x4 acc_hz = {0.f, 0.f, 0.f, 0.f};
    f32x4 acc_zt = {0.f, 0.f, 0.f, 0.f};
#pragma unroll
    for (int k4 = 0; k4 < 4; ++k4) {
      short8 ef = *reinterpret_cast<const short8*>(&sEz[zr][k4 * 32 + quad * 8]);
      acc_hz = __builtin_amdgcn_mfma_f32_16x16x32_bf16(hfrag[k4], ef, acc_hz, 0, 0, 0);
      acc_zt = __builtin_amdgcn_mfma_f32_16x16x32_bf16(tfrag[k4], ef, acc_zt, 0, 0, 0);
    }

    f32x4 gr[4];
#pragma unroll
    for (int i = 0; i < 4; ++i)
      gr[i] = *reinterpret_cast<const f32x4*>(&sGz[zr][i * 4]);
    const float g2v = sG2[zr];

#pragma unroll
    for (int reg = 0; reg < 4; ++reg) {
      const int b_loc = bhalf * 16 + quad * 4 + reg;
      const float hz = acc_hz[reg], zt = acc_zt[reg];
      const float sq2 = g2v + c2v[reg] - 2.f * zt;
      const float s2 = __builtin_amdgcn_sqrtf(fmaxf(sq2, 0.f));
      const float m2hz = -2.f * hz;
      float S1 = 0.f;
#pragma unroll
      for (int i = 0; i < 4; ++i) {
        f32x4 c1v = *reinterpret_cast<const f32x4*>(&sC1[b_loc][i * 4]);  // bcast
#pragma unroll
        for (int j = 0; j < 4; ++j) {
          const float sq1 = (c1v[j] + gr[i][j]) + m2hz;
          S1 += __builtin_amdgcn_sqrtf(fmaxf(sq1, 0.f));
        }
      }
      acc_out[reg] += S1 * s2;  // (-S1)*(-s2) = S1*s2
    }
  }

  // Reduce over the 16 n-lanes, then one atomic per (b, z-block).
#pragma unroll
  for (int reg = 0; reg < 4; ++reg) {
    float v = acc_out[reg];
    v += __shfl_xor(v, 1, 16);
    v += __shfl_xor(v, 2, 16);
    v += __shfl_xor(v, 4, 16);
    v += __shfl_xor(v, 8, 16);
    if (lm == 0)
      atomicAdd(&out[b_base + bhalf * 16 + quad * 4 + reg], v * scale);
  }
}

extern "C" void kernel_launch(void* const* d_in, const int* in_sizes, int n_in,
                              void* d_out, int out_size, void* d_ws, size_t ws_size,
                              hipStream_t stream) {
  const int* head  = (const int*)d_in[0];
  const int* tail  = (const int*)d_in[1];
  const int* qrel  = (const int*)d_in[2];
  // d_in[3] = depth (unused at depth==1 closed form)
  const float* Etab  = (const float*)d_in[4];
  const float* rules = (const float*)d_in[5];
  const int B = in_sizes[0];
  const int E = in_sizes[4] / 128;
  float* out = (float*)d_out;

  char* ws = (char*)d_ws;
  unsigned short* Ebf = (unsigned short*)ws;                       // E*128*2 B
  unsigned short* Hbf = (unsigned short*)(ws + (size_t)E * 256);   // B*128*2 B
  unsigned short* Tbf = Hbf + (size_t)B * 128;                     // B*128*2 B
  float* Gz = (float*)(ws + (size_t)E * 256 + (size_t)B * 512);    // E*16*4 B
  float* G2 = Gz + (size_t)E * 16;                                 // E*4 B
  float* C1 = G2 + E;                                              // B*16*4 B
  float* C2 = C1 + (size_t)B * 16;                                 // B*4 B

  const int nEB = E / 16;                                          // 512
  const int nBB = B / 16;                                          // 64
  ntp_pre<<<nEB + nBB, 256, 0, stream>>>(Etab, rules, head, tail, qrel, Ebf,
                                         Hbf, Tbf, Gz, G2, C1, C2, out, nEB);
  ntp_main<<<dim3(B / 32, E / 64), 256, 0, stream>>>(Ebf, Hbf, Tbf, Gz, G2, C1,
                                                     C2, out, E);
}